// Round 2
// baseline (2577.684 us; speedup 1.0000x reference)
//
#include <hip/hip_runtime.h>
#include <type_traits>

// LatentRecurrent persistent kernel v2: B=4096, Z=512, H=384, T=32, r=0.025
// BM=16 rows/block -> 256 blocks (fills all 256 CUs; v1 had 128 blocks = half idle).
// MFMA 16x16x32 f16 (acc f32x4: 28 VGPR for 7 tiles vs 64 for 4 f32x16 -> scheduler
// headroom), explicit 1-deep B-fragment prefetch to create memory-level parallelism.
// State: zf f32 [16][516] LDS master; per-lane f32 registers hold h and (z - z0)
// residual (each lane owns fixed (row,col) every step -> no epilogue global reads).
// MFMA 16x16x32 layouts: A: m=l&15, k=(l>>4)*8+j. B: n=l&15, same k.
// C/D: col=l&15, row=(l>>4)*4+reg   [measured m89]

typedef _Float16 f16;
typedef f16 f16x8 __attribute__((ext_vector_type(8)));
typedef float f32x4 __attribute__((ext_vector_type(4)));

#define ZD 512
#define HD 384
#define K2 768
#define TT 32
#define BM 16
#define LZ 516   // zf row stride (f32): 516 % 32 == 4 -> balanced banks for b128
#define LT 392   // tz/hb row stride (f16): 196 words % 32 == 4 -> balanced, 16B rows

__device__ __forceinline__ float lrelu(float x) { return x >= 0.f ? x : 0.01f * x; }

__global__ void cvt_f32_f16(const float* __restrict__ s, f16* __restrict__ d, int n) {
    for (int i = blockIdx.x * blockDim.x + threadIdx.x; i < n; i += gridDim.x * blockDim.x)
        d[i] = (f16)s[i];
}

__global__ __launch_bounds__(512) void latrec(
    const float* __restrict__ z0g, const float* __restrict__ h0g,
    const f16* __restrict__ W1h, const f16* __restrict__ W2h, const f16* __restrict__ W3h,
    const float* __restrict__ b1g, const float* __restrict__ b2g, const float* __restrict__ b3g,
    float* __restrict__ out)
{
    __shared__ float zf[BM * LZ];
    __shared__ f16 tz[BM * LT];
    __shared__ f16 hb[2][BM * LT];

    const int tid = threadIdx.x;
    const int w = tid >> 6, l = tid & 63;
    const int lm = l & 15;          // m (A) / n (B) / col (C) within 16-tile
    const int k0 = (l >> 4) * 8;    // k-offset of this lane's fragment
    const int rg0 = (l >> 4) * 4;   // first C/D row of this lane group
    const int m0 = blockIdx.x * BM;

    // ---- init: z slice (fp32) into LDS, zero out[:,0,:] ----
    for (int i = tid; i < BM * 128; i += 512) {
        int r = i >> 7, c = (i & 127) << 2;
        f32x4 v = *(const f32x4*)(z0g + (size_t)(m0 + r) * ZD + c);
        *(f32x4*)(zf + r * LZ + c) = v;
        float* op = out + (size_t)(m0 + r) * TT * ZD + c;
        __builtin_nontemporal_store(0.f, op + 0);
        __builtin_nontemporal_store(0.f, op + 1);
        __builtin_nontemporal_store(0.f, op + 2);
        __builtin_nontemporal_store(0.f, op + 3);
    }

    // ---- per-lane fixed tile columns, biases (registers), weight pointers, state ----
    // GEMM1: wave w owns n-tiles {w, w+8, w+16} of 24 (N=384)
    // GEMM2/3: z-tiles {w, w+8, w+16, w+24} of 32 (N=512), h-tiles {w, w+8, w+16} of 24 (N=384)
    int c1[3], cz[4], ch[3];
    float bv1[3], bvz[4], bvh[3];
    float hreg[3][4], rfz[4][4];
    const f16* w1p[3];
    const f16* wp[7];
    #pragma unroll
    for (int j = 0; j < 3; ++j) {
        c1[j] = (w + 8 * j) * 16 + lm;
        bv1[j] = b1g[c1[j]];
        w1p[j] = W1h + (size_t)c1[j] * ZD + k0;
    }
    #pragma unroll
    for (int i = 0; i < 4; ++i) {
        cz[i] = (w + 8 * i) * 16 + lm;
        bvz[i] = b2g[cz[i]];
        wp[i] = W2h + (size_t)cz[i] * K2 + k0;
        #pragma unroll
        for (int r = 0; r < 4; ++r) rfz[i][r] = 0.f;
    }
    #pragma unroll
    for (int i = 0; i < 3; ++i) {
        ch[i] = (w + 8 * i) * 16 + lm;
        bvh[i] = b3g[ch[i]];
        wp[4 + i] = W3h + (size_t)ch[i] * K2 + k0;
        #pragma unroll
        for (int r = 0; r < 4; ++r) {
            int row = rg0 + r;
            float hv = h0g[(size_t)(m0 + row) * HD + ch[i]];
            hreg[i][r] = hv;
            hb[0][row * LT + ch[i]] = (f16)hv;
        }
    }
    __syncthreads();

    for (int t = 1; t < TT; ++t) {
        const f16* hcur = hb[(t - 1) & 1];
        f16* hnxt = hb[t & 1];

        // ================= GEMM1: tz = f16(lrelu(z @ W1^T + b1)) =================
        {
            f32x4 ac[3] = {};
            const float* ap = zf + lm * LZ + k0;
            f16x8 cb[3];
            #pragma unroll
            for (int j = 0; j < 3; ++j) cb[j] = *(const f16x8*)(w1p[j]);
            #pragma unroll 4
            for (int ks = 0; ks < 15; ++ks) {
                f32x4 x0 = *(const f32x4*)(ap + ks * 32);
                f32x4 x1 = *(const f32x4*)(ap + ks * 32 + 4);
                f16x8 af;
                #pragma unroll
                for (int e = 0; e < 4; ++e) { af[e] = (f16)x0[e]; af[4 + e] = (f16)x1[e]; }
                f16x8 nb[3];
                #pragma unroll
                for (int j = 0; j < 3; ++j) nb[j] = *(const f16x8*)(w1p[j] + (ks + 1) * 32);
                #pragma unroll
                for (int j = 0; j < 3; ++j)
                    ac[j] = __builtin_amdgcn_mfma_f32_16x16x32_f16(af, cb[j], ac[j], 0, 0, 0);
                #pragma unroll
                for (int j = 0; j < 3; ++j) cb[j] = nb[j];
            }
            {   // tail iter ks=15 (already prefetched)
                f32x4 x0 = *(const f32x4*)(ap + 15 * 32);
                f32x4 x1 = *(const f32x4*)(ap + 15 * 32 + 4);
                f16x8 af;
                #pragma unroll
                for (int e = 0; e < 4; ++e) { af[e] = (f16)x0[e]; af[4 + e] = (f16)x1[e]; }
                #pragma unroll
                for (int j = 0; j < 3; ++j)
                    ac[j] = __builtin_amdgcn_mfma_f32_16x16x32_f16(af, cb[j], ac[j], 0, 0, 0);
            }
            #pragma unroll
            for (int j = 0; j < 3; ++j) {
                #pragma unroll
                for (int r = 0; r < 4; ++r)
                    tz[(rg0 + r) * LT + c1[j]] = (f16)lrelu(ac[j][r] + bv1[j]);
            }
        }
        __syncthreads();

        // ======== GEMM2/3 fused: N=896 (4 z-tiles + 3 h-tiles per wave), K=768 ========
        {
            f32x4 ac[7] = {};
            f16x8 cb[7];
            #pragma unroll
            for (int j = 0; j < 7; ++j) cb[j] = *(const f16x8*)(wp[j]);
            const f16* apz = tz + lm * LT + k0;
            const f16* aph = hcur + lm * LT + k0;

            auto khalf = [&](const f16* ap, int kw, auto TAILC) {
                constexpr bool TAIL = decltype(TAILC)::value;
                constexpr int NS = TAIL ? 11 : 12;
                #pragma unroll 4
                for (int ks = 0; ks < NS; ++ks) {
                    f16x8 af = *(const f16x8*)(ap + ks * 32);
                    f16x8 nb[7];
                    #pragma unroll
                    for (int j = 0; j < 7; ++j) nb[j] = *(const f16x8*)(wp[j] + kw + (ks + 1) * 32);
                    #pragma unroll
                    for (int j = 0; j < 7; ++j)
                        ac[j] = __builtin_amdgcn_mfma_f32_16x16x32_f16(af, cb[j], ac[j], 0, 0, 0);
                    #pragma unroll
                    for (int j = 0; j < 7; ++j) cb[j] = nb[j];
                }
                if constexpr (TAIL) {
                    f16x8 af = *(const f16x8*)(ap + 11 * 32);
                    #pragma unroll
                    for (int j = 0; j < 7; ++j)
                        ac[j] = __builtin_amdgcn_mfma_f32_16x16x32_f16(af, cb[j], ac[j], 0, 0, 0);
                }
            };
            // K 0..383 from tz (prefetch at ks=11 rolls into k=384 weights),
            // K 384..767 from h buffer
            khalf(apz, 0, std::integral_constant<bool, false>{});
            khalf(aph, 384, std::integral_constant<bool, true>{});

            // ---- epilogue z: zf += v, out = running residual (registers) ----
            #pragma unroll
            for (int i = 0; i < 4; ++i) {
                #pragma unroll
                for (int r = 0; r < 4; ++r) {
                    int row = rg0 + r;
                    float v = lrelu(ac[i][r] + bvz[i]) * 0.025f;
                    rfz[i][r] += v;
                    zf[row * LZ + cz[i]] += v;
                    __builtin_nontemporal_store(rfz[i][r],
                        out + ((size_t)(m0 + row) * TT + t) * ZD + cz[i]);
                }
            }
            // ---- epilogue h: f32 register state, f16 copy for next step's MFMA ----
            #pragma unroll
            for (int i = 0; i < 3; ++i) {
                #pragma unroll
                for (int r = 0; r < 4; ++r) {
                    int row = rg0 + r;
                    float v = lrelu(ac[4 + i][r] + bvh[i]) * 0.025f;
                    hreg[i][r] += v;
                    hnxt[row * LT + ch[i]] = (f16)hreg[i][r];
                }
            }
        }
        __syncthreads();
    }
}

extern "C" void kernel_launch(void* const* d_in, const int* in_sizes, int n_in,
                              void* d_out, int out_size, void* d_ws, size_t ws_size,
                              hipStream_t stream) {
    const float* z  = (const float*)d_in[0];
    const float* h0 = (const float*)d_in[1];
    const float* W1 = (const float*)d_in[2];
    const float* b1 = (const float*)d_in[3];
    const float* W2 = (const float*)d_in[4];
    const float* b2 = (const float*)d_in[5];
    const float* W3 = (const float*)d_in[6];
    const float* b3 = (const float*)d_in[7];
    float* out = (float*)d_out;

    char* p = (char*)d_ws;
    f16* W1h = (f16*)p; p += (size_t)HD * ZD * 2;
    f16* W2h = (f16*)p; p += (size_t)ZD * K2 * 2;
    f16* W3h = (f16*)p; p += (size_t)HD * K2 * 2;

    cvt_f32_f16<<<96, 256, 0, stream>>>(W1, W1h, HD * ZD);
    cvt_f32_f16<<<192, 256, 0, stream>>>(W2, W2h, ZD * K2);
    cvt_f32_f16<<<144, 256, 0, stream>>>(W3, W3h, HD * K2);

    latrec<<<4096 / BM, 512, 0, stream>>>(z, h0, W1h, W2h, W3h, b1, b2, b3, out);
}

// Round 3
// 2173.183 us; speedup vs baseline: 1.1861x; 1.1861x over previous
//
#include <hip/hip_runtime.h>
#include <type_traits>

// LatentRecurrent persistent kernel v3: B=4096, Z=512, H=384, T=32, r=0.025
// BM=16 rows/block -> 256 blocks (fills all 256 CUs).
// v2 post-mortem: 16-wide C-tile out stores = 64B half-line nt stores -> L2/L3
// write-allocate churn -> weights (1.77MB) evicted -> FETCH 3.58GB, 25% HBM miss
// on the serial weight chain. v3 routes out through LDS: cooperative full-line
// f32x4 stores of (zf - z0c) after each step. Weight streaming unchanged
// (L2-resident in v1 at identical access pattern).
// MFMA 16x16x32 f16. A: m=l&15, k=(l>>4)*8+j. B: n=l&15, same k.
// C/D: col=l&15, row=(l>>4)*4+reg   [measured m89]

typedef _Float16 f16;
typedef f16 f16x8 __attribute__((ext_vector_type(8)));
typedef float f32x4 __attribute__((ext_vector_type(4)));

#define ZD 512
#define HD 384
#define K2 768
#define TT 32
#define BM 16
#define LZ 516   // zf row stride (f32): 516 % 32 == 4 -> balanced banks for b128
#define LT 392   // tz/hb row stride (f16): 196 words % 32 == 4 -> balanced, 16B rows

__device__ __forceinline__ float lrelu(float x) { return x >= 0.f ? x : 0.01f * x; }

__global__ void cvt_f32_f16(const float* __restrict__ s, f16* __restrict__ d, int n) {
    for (int i = blockIdx.x * blockDim.x + threadIdx.x; i < n; i += gridDim.x * blockDim.x)
        d[i] = (f16)s[i];
}

__global__ __launch_bounds__(512) void latrec(
    const float* __restrict__ z0g, const float* __restrict__ h0g,
    const f16* __restrict__ W1h, const f16* __restrict__ W2h, const f16* __restrict__ W3h,
    const float* __restrict__ b1g, const float* __restrict__ b2g, const float* __restrict__ b3g,
    float* __restrict__ out)
{
    __shared__ float zf[BM * LZ];      // 33 KB  z master (f32)
    __shared__ float z0c[BM * ZD];     // 32 KB  z0 copy for residual
    __shared__ f16 tz[BM * LT];        // 12.25 KB
    __shared__ f16 hb[2][BM * LT];     // 24.5 KB

    const int tid = threadIdx.x;
    const int w = tid >> 6, l = tid & 63;
    const int lm = l & 15;          // m (A) / n (B) / col (C) within 16-tile
    const int k0 = (l >> 4) * 8;    // k-offset of this lane's fragment
    const int rg0 = (l >> 4) * 4;   // first C/D row of this lane group
    const int m0 = blockIdx.x * BM;

    // ---- init: z into zf + z0c, zero out[:,0,:] (full-line f32x4 stores) ----
    for (int i = tid; i < BM * 128; i += 512) {
        int r = i >> 7, c = (i & 127) << 2;
        f32x4 v = *(const f32x4*)(z0g + (size_t)(m0 + r) * ZD + c);
        *(f32x4*)(zf + r * LZ + c) = v;
        *(f32x4*)(z0c + r * ZD + c) = v;
        f32x4 zr = {0.f, 0.f, 0.f, 0.f};
        __builtin_nontemporal_store(zr, (f32x4*)(out + (size_t)(m0 + r) * TT * ZD + c));
    }

    // ---- per-lane fixed tile columns, biases (registers), weight pointers, state ----
    // GEMM1: wave w owns n-tiles {w, w+8, w+16} of 24 (N=384)
    // GEMM2/3: z-tiles {w, w+8, w+16, w+24} of 32 (N=512), h-tiles {w, w+8, w+16} of 24
    int c1[3], cz[4], ch[3];
    float bv1[3], bvz[4], bvh[3];
    float hreg[3][4];
    const f16* w1p[3];
    const f16* wp[7];
    #pragma unroll
    for (int j = 0; j < 3; ++j) {
        c1[j] = (w + 8 * j) * 16 + lm;
        bv1[j] = b1g[c1[j]];
        w1p[j] = W1h + (size_t)c1[j] * ZD + k0;
    }
    #pragma unroll
    for (int i = 0; i < 4; ++i) {
        cz[i] = (w + 8 * i) * 16 + lm;
        bvz[i] = b2g[cz[i]];
        wp[i] = W2h + (size_t)cz[i] * K2 + k0;
    }
    #pragma unroll
    for (int i = 0; i < 3; ++i) {
        ch[i] = (w + 8 * i) * 16 + lm;
        bvh[i] = b3g[ch[i]];
        wp[4 + i] = W3h + (size_t)ch[i] * K2 + k0;
        #pragma unroll
        for (int r = 0; r < 4; ++r) {
            int row = rg0 + r;
            float hv = h0g[(size_t)(m0 + row) * HD + ch[i]];
            hreg[i][r] = hv;
            hb[0][row * LT + ch[i]] = (f16)hv;
        }
    }
    __syncthreads();

    for (int t = 1; t < TT; ++t) {
        const f16* hcur = hb[(t - 1) & 1];
        f16* hnxt = hb[t & 1];

        // ================= GEMM1: tz = f16(lrelu(z @ W1^T + b1)) =================
        {
            f32x4 ac[3] = {};
            const float* ap = zf + lm * LZ + k0;
            f16x8 cb[3];
            #pragma unroll
            for (int j = 0; j < 3; ++j) cb[j] = *(const f16x8*)(w1p[j]);
            #pragma unroll 4
            for (int ks = 0; ks < 15; ++ks) {
                f32x4 x0 = *(const f32x4*)(ap + ks * 32);
                f32x4 x1 = *(const f32x4*)(ap + ks * 32 + 4);
                f16x8 af;
                #pragma unroll
                for (int e = 0; e < 4; ++e) { af[e] = (f16)x0[e]; af[4 + e] = (f16)x1[e]; }
                f16x8 nb[3];
                #pragma unroll
                for (int j = 0; j < 3; ++j) nb[j] = *(const f16x8*)(w1p[j] + (ks + 1) * 32);
                #pragma unroll
                for (int j = 0; j < 3; ++j)
                    ac[j] = __builtin_amdgcn_mfma_f32_16x16x32_f16(af, cb[j], ac[j], 0, 0, 0);
                #pragma unroll
                for (int j = 0; j < 3; ++j) cb[j] = nb[j];
            }
            {   // tail iter ks=15 (already prefetched)
                f32x4 x0 = *(const f32x4*)(ap + 15 * 32);
                f32x4 x1 = *(const f32x4*)(ap + 15 * 32 + 4);
                f16x8 af;
                #pragma unroll
                for (int e = 0; e < 4; ++e) { af[e] = (f16)x0[e]; af[4 + e] = (f16)x1[e]; }
                #pragma unroll
                for (int j = 0; j < 3; ++j)
                    ac[j] = __builtin_amdgcn_mfma_f32_16x16x32_f16(af, cb[j], ac[j], 0, 0, 0);
            }
            #pragma unroll
            for (int j = 0; j < 3; ++j) {
                #pragma unroll
                for (int r = 0; r < 4; ++r)
                    tz[(rg0 + r) * LT + c1[j]] = (f16)lrelu(ac[j][r] + bv1[j]);
            }
        }
        __syncthreads();

        // ======== GEMM2/3 fused: N=896 (4 z-tiles + 3 h-tiles per wave), K=768 ========
        {
            f32x4 ac[7] = {};
            f16x8 cb[7];
            #pragma unroll
            for (int j = 0; j < 7; ++j) cb[j] = *(const f16x8*)(wp[j]);
            const f16* apz = tz + lm * LT + k0;
            const f16* aph = hcur + lm * LT + k0;

            auto khalf = [&](const f16* ap, int kw, auto TAILC) {
                constexpr bool TAIL = decltype(TAILC)::value;
                constexpr int NS = TAIL ? 11 : 12;
                #pragma unroll 4
                for (int ks = 0; ks < NS; ++ks) {
                    f16x8 af = *(const f16x8*)(ap + ks * 32);
                    f16x8 nb[7];
                    #pragma unroll
                    for (int j = 0; j < 7; ++j) nb[j] = *(const f16x8*)(wp[j] + kw + (ks + 1) * 32);
                    #pragma unroll
                    for (int j = 0; j < 7; ++j)
                        ac[j] = __builtin_amdgcn_mfma_f32_16x16x32_f16(af, cb[j], ac[j], 0, 0, 0);
                    #pragma unroll
                    for (int j = 0; j < 7; ++j) cb[j] = nb[j];
                }
                if constexpr (TAIL) {
                    f16x8 af = *(const f16x8*)(ap + 11 * 32);
                    #pragma unroll
                    for (int j = 0; j < 7; ++j)
                        ac[j] = __builtin_amdgcn_mfma_f32_16x16x32_f16(af, cb[j], ac[j], 0, 0, 0);
                }
            };
            // K 0..383 from tz (prefetch at ks=11 rolls into k=384 weights),
            // K 384..767 from h buffer
            khalf(apz, 0, std::integral_constant<bool, false>{});
            khalf(aph, 384, std::integral_constant<bool, true>{});

            // ---- epilogue z: zf += v (LDS master; out store is cooperative below) ----
            #pragma unroll
            for (int i = 0; i < 4; ++i) {
                #pragma unroll
                for (int r = 0; r < 4; ++r) {
                    int row = rg0 + r;
                    float v = lrelu(ac[i][r] + bvz[i]) * 0.025f;
                    zf[row * LZ + cz[i]] += v;
                }
            }
            // ---- epilogue h: f32 register state, f16 copy for next step's MFMA ----
            #pragma unroll
            for (int i = 0; i < 3; ++i) {
                #pragma unroll
                for (int r = 0; r < 4; ++r) {
                    int row = rg0 + r;
                    float v = lrelu(ac[4 + i][r] + bvh[i]) * 0.025f;
                    hreg[i][r] += v;
                    hnxt[row * LT + ch[i]] = (f16)hreg[i][r];
                }
            }
        }
        __syncthreads();

        // ---- cooperative out store: full 128B lines, out = zf - z0 ----
        // (reads zf only; next iteration's GEMM1 also only reads zf, and the
        //  next zf write is after the GEMM1->GEMM2 barrier, so no extra sync)
        for (int i = tid; i < BM * 128; i += 512) {
            int r = i >> 7, c = (i & 127) << 2;
            f32x4 a = *(const f32x4*)(zf + r * LZ + c);
            f32x4 b = *(const f32x4*)(z0c + r * ZD + c);
            f32x4 d = a - b;
            __builtin_nontemporal_store(d,
                (f32x4*)(out + ((size_t)(m0 + r) * TT + t) * ZD + c));
        }
    }
}

extern "C" void kernel_launch(void* const* d_in, const int* in_sizes, int n_in,
                              void* d_out, int out_size, void* d_ws, size_t ws_size,
                              hipStream_t stream) {
    const float* z  = (const float*)d_in[0];
    const float* h0 = (const float*)d_in[1];
    const float* W1 = (const float*)d_in[2];
    const float* b1 = (const float*)d_in[3];
    const float* W2 = (const float*)d_in[4];
    const float* b2 = (const float*)d_in[5];
    const float* W3 = (const float*)d_in[6];
    const float* b3 = (const float*)d_in[7];
    float* out = (float*)d_out;

    char* p = (char*)d_ws;
    f16* W1h = (f16*)p; p += (size_t)HD * ZD * 2;
    f16* W2h = (f16*)p; p += (size_t)ZD * K2 * 2;
    f16* W3h = (f16*)p; p += (size_t)HD * K2 * 2;

    cvt_f32_f16<<<96, 256, 0, stream>>>(W1, W1h, HD * ZD);
    cvt_f32_f16<<<192, 256, 0, stream>>>(W2, W2h, ZD * K2);
    cvt_f32_f16<<<144, 256, 0, stream>>>(W3, W3h, HD * K2);

    latrec<<<4096 / BM, 512, 0, stream>>>(z, h0, W1h, W2h, W3h, b1, b2, b3, out);
}